// Round 1
// baseline (842.328 us; speedup 1.0000x reference)
//
#include <hip/hip_runtime.h>

#define DIM 64

// Kernel 1: COO SpMM scatter-add.  x[r,:] += v * feat[c,:]
// One wave (64 lanes) per edge: lane d handles dim d.
// Edge-index loads are same-address across the wave -> single cacheline req.
// feat row read is one coalesced 256B read; atomicAdd is device-scope fp32.
__global__ __launch_bounds__(256) void scatter_kernel(
    const int* __restrict__ rows, const int* __restrict__ cols,
    const float* __restrict__ vals, const float* __restrict__ feat,
    float* __restrict__ x, int E)
{
    unsigned long long t = (unsigned long long)blockIdx.x * blockDim.x + threadIdx.x;
    int e = (int)(t >> 6);
    int d = (int)(t & 63);
    if (e >= E) return;
    int r = rows[e];
    int c = cols[e];
    float v = vals[e];
    float f = feat[(size_t)c * DIM + d];
    atomicAdd(&x[(size_t)r * DIM + d], v * f);
}

// Kernel 2: out = (f+x)@W1 + (f*x)@W2 + (b1+b2)
// Wave-per-node, lane = output column j.
// Each lane holds W1[:,j] and W2[:,j] in 128 VGPRs (loaded once, amortized
// over the grid-stride node loop). Per-node activations a=f+x, b=f*x are
// broadcast lane->wave with v_readlane (no LDS, no shuffle-network cost).
__global__ __launch_bounds__(256) void transform_kernel(
    const float* __restrict__ feat, const float* __restrict__ x,
    const float* __restrict__ W1, const float* __restrict__ b1,
    const float* __restrict__ W2, const float* __restrict__ b2,
    float* __restrict__ out, int N)
{
    const int lane = threadIdx.x & 63;

    float w1c[DIM], w2c[DIM];
#pragma unroll
    for (int k = 0; k < DIM; ++k) {
        w1c[k] = W1[k * DIM + lane];   // column `lane` of W1
        w2c[k] = W2[k * DIM + lane];
    }
    const float bsum = b1[lane] + b2[lane];

    const int wave   = (int)((blockIdx.x * blockDim.x + threadIdx.x) >> 6);
    const int nwaves = (int)((gridDim.x * blockDim.x) >> 6);

    for (int n = wave; n < N; n += nwaves) {
        float f  = feat[n * DIM + lane];
        float xv = x[n * DIM + lane];
        float a = f + xv;    // (features + x)
        float b = f * xv;    // (x * features)
        float acc = bsum;
#pragma unroll
        for (int k = 0; k < DIM; ++k) {
            float ak = __builtin_bit_cast(float,
                __builtin_amdgcn_readlane(__builtin_bit_cast(int, a), k));
            float bk = __builtin_bit_cast(float,
                __builtin_amdgcn_readlane(__builtin_bit_cast(int, b), k));
            acc = fmaf(ak, w1c[k], acc);
            acc = fmaf(bk, w2c[k], acc);
        }
        out[n * DIM + lane] = acc;
    }
}

extern "C" void kernel_launch(void* const* d_in, const int* in_sizes, int n_in,
                              void* d_out, int out_size, void* d_ws, size_t ws_size,
                              hipStream_t stream)
{
    const int*   rows = (const int*)d_in[0];
    const int*   cols = (const int*)d_in[1];
    const float* vals = (const float*)d_in[2];
    const float* feat = (const float*)d_in[3];
    const float* W1   = (const float*)d_in[4];
    const float* b1   = (const float*)d_in[5];
    const float* W2   = (const float*)d_in[6];
    const float* b2   = (const float*)d_in[7];
    float* out = (float*)d_out;

    const int E = in_sizes[0];
    const int N = in_sizes[3] / DIM;

    float* x = (float*)d_ws;              // N*DIM fp32 accumulator (25.6 MB)

    // d_ws is re-poisoned to 0xAA before every timed launch -> must zero it.
    hipMemsetAsync(x, 0, (size_t)N * DIM * sizeof(float), stream);

    {
        unsigned long long threads = (unsigned long long)E * DIM;
        unsigned int blocks = (unsigned int)((threads + 255ull) / 256ull);
        scatter_kernel<<<blocks, 256, 0, stream>>>(rows, cols, vals, feat, x, E);
    }
    {
        transform_kernel<<<2048, 256, 0, stream>>>(feat, x, W1, b1, W2, b2, out, N);
    }
}

// Round 2
// 689.773 us; speedup vs baseline: 1.2212x; 1.2212x over previous
//
#include <hip/hip_runtime.h>

#define DIM 64
#define NPAD 256  // alignment pad

// ---------- fallback (round-1) atomic scatter ----------
__global__ __launch_bounds__(256) void scatter_kernel(
    const int* __restrict__ rows, const int* __restrict__ cols,
    const float* __restrict__ vals, const float* __restrict__ feat,
    float* __restrict__ x, int E)
{
    unsigned long long t = (unsigned long long)blockIdx.x * blockDim.x + threadIdx.x;
    int e = (int)(t >> 6);
    int d = (int)(t & 63);
    if (e >= E) return;
    int r = rows[e];
    int c = cols[e];
    float v = vals[e];
    float f = feat[(size_t)c * DIM + d];
    atomicAdd(&x[(size_t)r * DIM + d], v * f);
}

// ---------- sort-by-row pipeline ----------

// counts[r]++ for each edge (counts aliases offs buffer, pre-zeroed)
__global__ __launch_bounds__(256) void hist_kernel(
    const int* __restrict__ rows, int* __restrict__ counts, int E)
{
    int e = blockIdx.x * blockDim.x + threadIdx.x;
    if (e < E) atomicAdd(&counts[rows[e]], 1);
}

// Per-block exclusive scan over 1024 elements (256 thr x 4). In-place safe:
// each block reads only its own range before its writes.
__global__ __launch_bounds__(256) void scan_blocks(
    int* __restrict__ offs, int* __restrict__ bsums, int n)
{
    __shared__ int lds[256];
    int b = blockIdx.x, t = threadIdx.x;
    int base = b * 1024 + t * 4;
    int e0 = (base + 0 < n) ? offs[base + 0] : 0;
    int e1 = (base + 1 < n) ? offs[base + 1] : 0;
    int e2 = (base + 2 < n) ? offs[base + 2] : 0;
    int e3 = (base + 3 < n) ? offs[base + 3] : 0;
    int s = e0 + e1 + e2 + e3;
    lds[t] = s;
    __syncthreads();
    for (int off = 1; off < 256; off <<= 1) {
        int v = (t >= off) ? lds[t - off] : 0;
        __syncthreads();
        lds[t] += v;
        __syncthreads();
    }
    int excl = lds[t] - s;
    if (t == 255) bsums[b] = lds[255];
    if (base + 0 < n) offs[base + 0] = excl;
    if (base + 1 < n) offs[base + 1] = excl + e0;
    if (base + 2 < n) offs[base + 2] = excl + e0 + e1;
    if (base + 3 < n) offs[base + 3] = excl + e0 + e1 + e2;
}

// exclusive scan of <=256 block sums, single block
__global__ __launch_bounds__(256) void scan_bsums(int* __restrict__ bsums, int nb)
{
    __shared__ int lds[256];
    int t = threadIdx.x;
    int v = (t < nb) ? bsums[t] : 0;
    lds[t] = v;
    __syncthreads();
    for (int off = 1; off < 256; off <<= 1) {
        int u = (t >= off) ? lds[t - off] : 0;
        __syncthreads();
        lds[t] += u;
        __syncthreads();
    }
    if (t < nb) bsums[t] = lds[t] - v;
}

__global__ __launch_bounds__(256) void add_offsets(
    int* __restrict__ offs, const int* __restrict__ bsums, int n, int total)
{
    int b = blockIdx.x, t = threadIdx.x;
    int base = b * 1024 + t * 4;
    int add = bsums[b];
#pragma unroll
    for (int k = 0; k < 4; ++k)
        if (base + k < n) offs[base + k] += add;
    if (b == 0 && t == 0) offs[n] = total;
}

// scatter (col,val) pairs into row-sorted order
__global__ __launch_bounds__(256) void place_kernel(
    const int* __restrict__ rows, const int* __restrict__ cols,
    const float* __restrict__ vals, int* __restrict__ cursors,
    unsigned long long* __restrict__ sorted, int E)
{
    int e = blockIdx.x * blockDim.x + threadIdx.x;
    if (e >= E) return;
    int r = rows[e];
    int pos = atomicAdd(&cursors[r], 1);
    unsigned long long pk =
        ((unsigned long long)__float_as_uint(vals[e]) << 32) | (unsigned)cols[e];
    sorted[pos] = pk;
}

// wave per row: contention-free gather-reduce, single coalesced write of x row
__global__ __launch_bounds__(256) void reduce_kernel(
    const unsigned long long* __restrict__ sorted, const int* __restrict__ offs,
    const float* __restrict__ feat, float* __restrict__ x, int N)
{
    int wid  = (int)((blockIdx.x * blockDim.x + threadIdx.x) >> 6);
    int lane = threadIdx.x & 63;
    if (wid >= N) return;
    int s = offs[wid], t = offs[wid + 1];
    float acc0 = 0.f, acc1 = 0.f;
    int i = s;
    for (; i + 1 < t; i += 2) {
        unsigned long long p0 = sorted[i];
        unsigned long long p1 = sorted[i + 1];
        int   c0 = (int)(p0 & 0xffffffffu);
        float v0 = __uint_as_float((unsigned)(p0 >> 32));
        int   c1 = (int)(p1 & 0xffffffffu);
        float v1 = __uint_as_float((unsigned)(p1 >> 32));
        acc0 = fmaf(v0, feat[(size_t)c0 * DIM + lane], acc0);
        acc1 = fmaf(v1, feat[(size_t)c1 * DIM + lane], acc1);
    }
    if (i < t) {
        unsigned long long p0 = sorted[i];
        int   c0 = (int)(p0 & 0xffffffffu);
        float v0 = __uint_as_float((unsigned)(p0 >> 32));
        acc0 = fmaf(v0, feat[(size_t)c0 * DIM + lane], acc0);
    }
    x[(size_t)wid * DIM + lane] = acc0 + acc1;
}

// out = (f+x)@W1 + (f*x)@W2 + (b1+b2), wave-per-node, W columns in VGPRs
__global__ __launch_bounds__(256) void transform_kernel(
    const float* __restrict__ feat, const float* __restrict__ x,
    const float* __restrict__ W1, const float* __restrict__ b1,
    const float* __restrict__ W2, const float* __restrict__ b2,
    float* __restrict__ out, int N)
{
    const int lane = threadIdx.x & 63;

    float w1c[DIM], w2c[DIM];
#pragma unroll
    for (int k = 0; k < DIM; ++k) {
        w1c[k] = W1[k * DIM + lane];
        w2c[k] = W2[k * DIM + lane];
    }
    const float bsum = b1[lane] + b2[lane];

    const int wave   = (int)((blockIdx.x * blockDim.x + threadIdx.x) >> 6);
    const int nwaves = (int)((gridDim.x * blockDim.x) >> 6);

    for (int n = wave; n < N; n += nwaves) {
        float f  = feat[n * DIM + lane];
        float xv = x[n * DIM + lane];
        float a = f + xv;
        float b = f * xv;
        float acc = bsum;
#pragma unroll
        for (int k = 0; k < DIM; ++k) {
            float ak = __builtin_bit_cast(float,
                __builtin_amdgcn_readlane(__builtin_bit_cast(int, a), k));
            float bk = __builtin_bit_cast(float,
                __builtin_amdgcn_readlane(__builtin_bit_cast(int, b), k));
            acc = fmaf(ak, w1c[k], acc);
            acc = fmaf(bk, w2c[k], acc);
        }
        out[n * DIM + lane] = acc;
    }
}

extern "C" void kernel_launch(void* const* d_in, const int* in_sizes, int n_in,
                              void* d_out, int out_size, void* d_ws, size_t ws_size,
                              hipStream_t stream)
{
    const int*   rows = (const int*)d_in[0];
    const int*   cols = (const int*)d_in[1];
    const float* vals = (const float*)d_in[2];
    const float* feat = (const float*)d_in[3];
    const float* W1   = (const float*)d_in[4];
    const float* b1   = (const float*)d_in[5];
    const float* W2   = (const float*)d_in[6];
    const float* b2   = (const float*)d_in[7];
    float* out = (float*)d_out;

    const int E = in_sizes[0];
    const int N = in_sizes[3] / DIM;

    // workspace layout
    char* ws = (char*)d_ws;
    size_t xBytes      = (size_t)N * DIM * sizeof(float);          // 25.6 MB
    size_t offsBytes   = ((size_t)(N + 1) * sizeof(int) + NPAD - 1) / NPAD * NPAD;
    size_t cursBytes   = ((size_t)N * sizeof(int) + NPAD - 1) / NPAD * NPAD;
    size_t bsumBytes   = 256 * sizeof(int);
    size_t sortedBytes = (size_t)E * 8;                            // 25.6 MB

    float*              x       = (float*)ws;
    int*                offs    = (int*)(ws + xBytes);
    int*                cursors = (int*)(ws + xBytes + offsBytes);
    int*                bsums   = (int*)(ws + xBytes + offsBytes + cursBytes);
    unsigned long long* sorted  = (unsigned long long*)(ws + xBytes + offsBytes + cursBytes + bsumBytes);
    size_t need = xBytes + offsBytes + cursBytes + bsumBytes + sortedBytes;

    const int NB1 = (N + 1023) / 1024;   // blocks for the 1024-elem scan

    if (ws_size >= need && NB1 <= 256) {
        // ----- sort-by-row pipeline (no fp32 atomics) -----
        hipMemsetAsync(offs, 0, (size_t)(N + 1) * sizeof(int), stream);
        hist_kernel<<<(E + 255) / 256, 256, 0, stream>>>(rows, offs, E);
        scan_blocks<<<NB1, 256, 0, stream>>>(offs, bsums, N);
        scan_bsums<<<1, 256, 0, stream>>>(bsums, NB1);
        add_offsets<<<NB1, 256, 0, stream>>>(offs, bsums, N, E);
        hipMemcpyAsync(cursors, offs, (size_t)N * sizeof(int),
                       hipMemcpyDeviceToDevice, stream);
        place_kernel<<<(E + 255) / 256, 256, 0, stream>>>(rows, cols, vals,
                                                          cursors, sorted, E);
        reduce_kernel<<<(N * 64 + 255) / 256, 256, 0, stream>>>(sorted, offs,
                                                                feat, x, N);
    } else {
        // ----- fallback: atomic scatter -----
        hipMemsetAsync(x, 0, xBytes, stream);
        unsigned long long threads = (unsigned long long)E * DIM;
        unsigned int blocks = (unsigned int)((threads + 255ull) / 256ull);
        scatter_kernel<<<blocks, 256, 0, stream>>>(rows, cols, vals, feat, x, E);
    }

    transform_kernel<<<2048, 256, 0, stream>>>(feat, x, W1, b1, W2, b2, out, N);
}